// Round 3
// baseline (215.347 us; speedup 1.0000x reference)
//
#include <hip/hip_runtime.h>
#include <hip/hip_bf16.h>

typedef __attribute__((ext_vector_type(8))) short short8;
typedef __attribute__((ext_vector_type(4))) float f32x4;
typedef unsigned short ushort_t;

__device__ __forceinline__ ushort_t f2bf(float f) {
    union { __hip_bfloat16 h; ushort_t u; } c;
    c.h = __float2bfloat16(f);
    return c.u;
}

__device__ __forceinline__ void gload16(const ushort_t* g, ushort_t* l) {
    __builtin_amdgcn_global_load_lds(
        (const __attribute__((address_space(1))) void*)g,
        (__attribute__((address_space(3))) void*)l, 16, 0, 0);
}

// ---------------- convert x fp32 -> bf16 ----------------
__global__ __launch_bounds__(256) void k_convert_x(const float* __restrict__ x,
                                                   ushort_t* __restrict__ xb) {
    size_t idx = ((size_t)blockIdx.x * 256 + threadIdx.x) * 8;
    float4 a = *(const float4*)(x + idx);
    float4 b = *(const float4*)(x + idx + 4);
    short8 o;
    o[0] = (short)f2bf(a.x); o[1] = (short)f2bf(a.y);
    o[2] = (short)f2bf(a.z); o[3] = (short)f2bf(a.w);
    o[4] = (short)f2bf(b.x); o[5] = (short)f2bf(b.y);
    o[6] = (short)f2bf(b.z); o[7] = (short)f2bf(b.w);
    *(short8*)(xb + idx) = o;
}

// ---------------- transpose W fp32 [d][e] -> bf16 Wt [e][d], 3 weights -------
__global__ __launch_bounds__(256) void k_transpose_w(const float* __restrict__ W0,
                                                     const float* __restrict__ W1,
                                                     const float* __restrict__ W2,
                                                     ushort_t* __restrict__ Wt) {
    const float* W = (blockIdx.z == 0) ? W0 : (blockIdx.z == 1) ? W1 : W2;
    ushort_t* out = Wt + (size_t)blockIdx.z * 1024 * 1024;
    __shared__ float tile[32][33];
    int tx = threadIdx.x, ty = threadIdx.y;            // 32 x 8
    int d0 = blockIdx.y * 32, e0 = blockIdx.x * 32;
#pragma unroll
    for (int i = 0; i < 32; i += 8)
        tile[ty + i][tx] = W[(size_t)(d0 + ty + i) * 1024 + e0 + tx];
    __syncthreads();
#pragma unroll
    for (int i = 0; i < 32; i += 8)
        out[(size_t)(e0 + ty + i) * 1024 + d0 + tx] = f2bf(tile[tx][ty + i]);
}

// ---------------- transpose V bf16 [b][j][e] -> Vt [b][e][j] ----------------
__global__ __launch_bounds__(256) void k_transpose_v(const ushort_t* __restrict__ V,
                                                     ushort_t* __restrict__ Vt) {
    int b = blockIdx.z;
    const ushort_t* in = V + (size_t)b * 2048 * 1024;
    ushort_t* out = Vt + (size_t)b * 1024 * 2048;
    __shared__ ushort_t tile[32][33];
    int tx = threadIdx.x, ty = threadIdx.y;            // 32 x 8
    int e0 = blockIdx.x * 32, j0 = blockIdx.y * 32;
#pragma unroll
    for (int i = 0; i < 32; i += 8)
        tile[ty + i][tx] = in[(size_t)(j0 + ty + i) * 1024 + e0 + tx];
    __syncthreads();
#pragma unroll
    for (int i = 0; i < 32; i += 8)
        out[(size_t)(e0 + ty + i) * 2048 + j0 + tx] = tile[tx][ty + i];
}

// ---------------- proj GEMM: 256x128 tile, 8-wave, counted-vmcnt pipeline ----
// C[8192][1024](bf16, per z) = xb[8192][1024] * Wt[z][1024][1024]^T
// K-half staging: per K-tile (BK=64) four "halves": s=4t+{0:Ak0,1:Bk0,2:Ak1,3:Bk1}
// A half = [256][32] bf16 (16KB, 2 gload16/thr), B half = [128][32] (8KB, 1).
// Phase p (2 per K-tile): reads halves <= 2p+1; issues halves {2p+6, 2p+7};
// vmcnt(6) leaves newest 4 halves (2A+2B = 6 ops) in flight. Never drains.
// Swizzle: LDS elem col ce = gcol ^ ((row&3)<<3) on both stage-src and read.
__global__ __launch_bounds__(512, 2) void k_proj256(const ushort_t* __restrict__ Abase,
                                                    const ushort_t* __restrict__ Bbase,
                                                    ushort_t* __restrict__ Cbase) {
    const int bm = blockIdx.x, bn = blockIdx.y, bz = blockIdx.z;
    const ushort_t* A = Abase;
    const ushort_t* B = Bbase + (size_t)bz * 1048576;
    constexpr int LDA = 1024, LDB = 1024, NT = 16;

    __shared__ ushort_t Asm[2][2][8192];   // [dbuf][khalf][256*32]  64KB
    __shared__ ushort_t Bsm[2][2][4096];   // [dbuf][khalf][128*32]  32KB

    const int tid = threadIdx.x;
    const int l = tid & 63, w = tid >> 6;
    const int wrow = w >> 2, wcol = w & 3;      // 2 x 4 wave grid
    const int lr = l & 15, lg = l >> 4;
    const int axoff = (lg * 8) ^ ((lr & 3) << 3);

    const int srow = tid >> 2;                  // 0..127
    const int scol = ((tid & 3) * 8) ^ (((tid >> 2) & 3) << 3);
    const ushort_t* Ag = A + (size_t)(bm * 256 + srow) * LDA + scol;
    const ushort_t* Bg = B + (size_t)(bn * 128 + srow) * LDB + scol;

    auto stage = [&](int s) {
        if (s >= 4 * NT) return;
        const int ts = s >> 2, j = s & 3, kh = j >> 1, db = ts & 1;
        if (j & 1) {
            gload16(Bg + ts * 64 + kh * 32, &Bsm[db][kh][tid * 8]);
        } else {
            const ushort_t* src = Ag + ts * 64 + kh * 32;
            gload16(src, &Asm[db][kh][tid * 8]);
            gload16(src + (size_t)128 * LDA, &Asm[db][kh][tid * 8 + 4096]);
        }
    };

    f32x4 zero = {0.f, 0.f, 0.f, 0.f};
    f32x4 acc[8][2];
#pragma unroll
    for (int m = 0; m < 8; ++m) { acc[m][0] = zero; acc[m][1] = zero; }

    // prologue: halves 0..5 (tile0 complete + tile1 k0)
    stage(0); stage(1); stage(2); stage(3); stage(4); stage(5);
    asm volatile("s_waitcnt vmcnt(6)" ::: "memory");
    __builtin_amdgcn_s_barrier();

#pragma unroll 4
    for (int p = 0; p < 2 * NT; ++p) {
        const int kh = p & 1, db = (p >> 1) & 1;
        short8 a[8], b[2];
#pragma unroll
        for (int m = 0; m < 8; ++m)
            a[m] = *(const short8*)&Asm[db][kh][(wrow * 128 + m * 16 + lr) * 32 + axoff];
#pragma unroll
        for (int n = 0; n < 2; ++n)
            b[n] = *(const short8*)&Bsm[db][kh][(wcol * 32 + n * 16 + lr) * 32 + axoff];
        stage(2 * p + 6);
        stage(2 * p + 7);
        __builtin_amdgcn_s_setprio(1);
#pragma unroll
        for (int m = 0; m < 8; ++m)
#pragma unroll
            for (int n = 0; n < 2; ++n)
                acc[m][n] = __builtin_amdgcn_mfma_f32_16x16x32_bf16(a[m], b[n], acc[m][n], 0, 0, 0);
        __builtin_amdgcn_s_setprio(0);
        asm volatile("s_waitcnt vmcnt(6)" ::: "memory");
        __builtin_amdgcn_s_barrier();
    }
    asm volatile("s_waitcnt vmcnt(0)" ::: "memory");  // drain before LDS dealloc

    ushort_t* C = Cbase + (size_t)bz * 8388608;
    const int rb = lg * 4;
#pragma unroll
    for (int m = 0; m < 8; ++m)
#pragma unroll
        for (int n = 0; n < 2; ++n) {
            int gcol = bn * 128 + wcol * 32 + n * 16 + lr;
#pragma unroll
            for (int r = 0; r < 4; ++r) {
                int grow = bm * 256 + wrow * 128 + m * 16 + rb + r;
                C[(size_t)grow * 1024 + gcol] = f2bf(acc[m][n][r]);
            }
        }
}

// ---------------- GEMM (m97 128x128): C = A * B^T ----------------
// MODE 1: qk    A=Q[b][2048][1024]    B=K[b][2048][1024]   C=scores fp32 (*1/32, causal)
// MODE 2: pv    A=P bf16 lda=4096     B=Vt[b][1024][2048]  C=out fp32, K-range causal
template <int MODE>
__global__ __launch_bounds__(256) void k_gemm(const ushort_t* __restrict__ Abase,
                                              const ushort_t* __restrict__ Bbase,
                                              void* __restrict__ Cbase) {
    const int bm = blockIdx.x, bn = blockIdx.y, bz = blockIdx.z;

    const ushort_t* A;
    const ushort_t* B;
    int lda, ldb, nk;
    if constexpr (MODE == 1) {
        if (bn > bm) return;  // fully-masked causal tile
        A = Abase + (size_t)bz * 2048 * 1024; lda = 1024;
        B = Bbase + (size_t)bz * 2048 * 1024; ldb = 1024;
        nk = 32;
    } else {
        A = Abase + (size_t)bz * 2048 * 4096; lda = 4096;
        B = Bbase + (size_t)bz * 1024 * 2048; ldb = 2048;
        nk = (bm + 1) * 4;  // causal K truncation: j <= bm*128+127
    }

    __shared__ ushort_t As[128 * 32];   // linear (gload_lds dest)
    __shared__ ushort_t Bs[128 * 32];

    const int tid = threadIdx.x;
    const int l = tid & 63, wid = tid >> 6;
    const int wr = (wid >> 1) * 64, wc = (wid & 1) * 64;
    const int lr = l & 15, kc = (l >> 4) * 8;

    const int srow = tid >> 2, skb = (tid & 3) * 8;
    const ushort_t* ag = A + (size_t)(bm * 128 + srow) * lda + skb;
    const ushort_t* bg = B + (size_t)(bn * 128 + srow) * ldb + skb;
    const size_t a64 = (size_t)64 * lda, b64 = (size_t)64 * ldb;
    ushort_t* al = As + tid * 8;
    ushort_t* bl = Bs + tid * 8;

    f32x4 zero = {0.f, 0.f, 0.f, 0.f};
    f32x4 acc[4][4];
#pragma unroll
    for (int m = 0; m < 4; ++m)
#pragma unroll
        for (int n = 0; n < 4; ++n) acc[m][n] = zero;

    for (int ks = 0; ks < nk; ++ks) {
        __syncthreads();
        gload16(ag, al);
        gload16(ag + a64, al + 2048);
        gload16(bg, bl);
        gload16(bg + b64, bl + 2048);
        ag += 32; bg += 32;
        __syncthreads();

        short8 a[4], b[4];
#pragma unroll
        for (int m = 0; m < 4; ++m)
            a[m] = *(const short8*)&As[(wr + m * 16 + lr) * 32 + kc];
#pragma unroll
        for (int n = 0; n < 4; ++n)
            b[n] = *(const short8*)&Bs[(wc + n * 16 + lr) * 32 + kc];
#pragma unroll
        for (int m = 0; m < 4; ++m)
#pragma unroll
            for (int n = 0; n < 4; ++n)
                acc[m][n] = __builtin_amdgcn_mfma_f32_16x16x32_bf16(a[m], b[n], acc[m][n], 0, 0, 0);
    }

    const int rbase = (l >> 4) * 4;
    const int cbase = l & 15;
#pragma unroll
    for (int m = 0; m < 4; ++m) {
#pragma unroll
        for (int n = 0; n < 4; ++n) {
            int row0 = wr + m * 16 + rbase;
            int col = wc + n * 16 + cbase;
            int gcol = bn * 128 + col;
#pragma unroll
            for (int r = 0; r < 4; ++r) {
                int grow = bm * 128 + row0 + r;
                float v = acc[m][n][r];
                if constexpr (MODE == 1) {
                    float* C = (float*)Cbase + (size_t)bz * 2048 * 2048;
                    if (gcol <= grow) C[(size_t)grow * 2048 + gcol] = v * 0.03125f;
                } else {
                    float* C = (float*)Cbase + (size_t)bz * 2048 * 1024;
                    C[(size_t)grow * 1024 + gcol] = v;
                }
            }
        }
    }
}

// ---------------- row softmax: fp32 scores row -> normalized bf16 P in place -
__global__ __launch_bounds__(256) void k_softmax(float* __restrict__ scores) {
    const int t = blockIdx.x;        // global row 0..8191
    const int i = t & 2047;          // row within batch (causal limit)
    float* row = scores + (size_t)t * 2048;
    const int tid = threadIdx.x;
    const int j0 = tid * 8;

    float4 f0 = *(const float4*)(row + j0);
    float4 f1 = *(const float4*)(row + j0 + 4);
    float v[8] = {f0.x, f0.y, f0.z, f0.w, f1.x, f1.y, f1.z, f1.w};

    float m = -3.0e38f;
#pragma unroll
    for (int e = 0; e < 8; ++e)
        if (j0 + e <= i) m = fmaxf(m, v[e]);
#pragma unroll
    for (int off = 32; off > 0; off >>= 1) m = fmaxf(m, __shfl_down(m, off, 64));

    __shared__ float redm[4];
    __shared__ float reds[4];
    const int lane = tid & 63, wid = tid >> 6;
    if (lane == 0) redm[wid] = m;
    __syncthreads();
    m = fmaxf(fmaxf(redm[0], redm[1]), fmaxf(redm[2], redm[3]));

    float p[8];
    float s = 0.f;
#pragma unroll
    for (int e = 0; e < 8; ++e) {
        p[e] = (j0 + e <= i) ? __expf(v[e] - m) : 0.f;
        s += p[e];
    }
#pragma unroll
    for (int off = 32; off > 0; off >>= 1) s += __shfl_down(s, off, 64);
    if (lane == 0) reds[wid] = s;
    __syncthreads();
    s = reds[0] + reds[1] + reds[2] + reds[3];
    float inv = 1.f / s;

    short8 o;
#pragma unroll
    for (int e = 0; e < 8; ++e) o[e] = (short)f2bf(p[e] * inv);
    *(short8*)((ushort_t*)row + j0) = o;   // bf16 row, stride 4096 elems
}

extern "C" void kernel_launch(void* const* d_in, const int* in_sizes, int n_in,
                              void* d_out, int out_size, void* d_ws, size_t ws_size,
                              hipStream_t stream) {
    const float* x  = (const float*)d_in[0];
    const float* Wq = (const float*)d_in[1];
    const float* Wk = (const float*)d_in[2];
    const float* Wv = (const float*)d_in[3];

    char* ws = (char*)d_ws;
    ushort_t* xb     = (ushort_t*)(ws);                 // 16 MB
    ushort_t* Wt     = (ushort_t*)(ws + 16777216);      // 6 MB  [3][1024][1024]
    ushort_t* QKV    = (ushort_t*)(ws + 23068672);      // 48 MB [3][8192][1024]
    ushort_t* Vt     = (ushort_t*)(ws + 73400320);      // 16 MB [4][1024][2048]
    float*    scores = (float*)   (ws + 90177536);      // 64 MB [4][2048][2048] fp32 / P bf16

    ushort_t* Q = QKV;
    ushort_t* K = QKV + (size_t)8192 * 1024;
    ushort_t* V = QKV + (size_t)2 * 8192 * 1024;

    k_convert_x<<<4096, 256, 0, stream>>>(x, xb);
    k_transpose_w<<<dim3(32, 32, 3), dim3(32, 8), 0, stream>>>(Wq, Wk, Wv, Wt);
    k_proj256<<<dim3(32, 8, 3), 512, 0, stream>>>(xb, Wt, QKV);
    k_transpose_v<<<dim3(32, 64, 4), dim3(32, 8), 0, stream>>>(V, Vt);
    k_gemm<1><<<dim3(16, 16, 4), 256, 0, stream>>>(Q, K, scores);
    k_softmax<<<8192, 256, 0, stream>>>(scores);
    k_gemm<2><<<dim3(16, 8, 4), 256, 0, stream>>>((const ushort_t*)scores, Vt, (float*)d_out);
}

// Round 4
// 204.241 us; speedup vs baseline: 1.0544x; 1.0544x over previous
//
#include <hip/hip_runtime.h>
#include <hip/hip_bf16.h>

typedef __attribute__((ext_vector_type(8))) short short8;
typedef __attribute__((ext_vector_type(4))) float f32x4;
typedef unsigned short ushort_t;

__device__ __forceinline__ ushort_t f2bf(float f) {
    union { __hip_bfloat16 h; ushort_t u; } c;
    c.h = __float2bfloat16(f);
    return c.u;
}

__device__ __forceinline__ void gload16(const ushort_t* g, ushort_t* l) {
    __builtin_amdgcn_global_load_lds(
        (const __attribute__((address_space(1))) void*)g,
        (__attribute__((address_space(3))) void*)l, 16, 0, 0);
}

// ---------------- convert x fp32 -> bf16 ----------------
__global__ __launch_bounds__(256) void k_convert_x(const float* __restrict__ x,
                                                   ushort_t* __restrict__ xb) {
    size_t idx = ((size_t)blockIdx.x * 256 + threadIdx.x) * 8;
    float4 a = *(const float4*)(x + idx);
    float4 b = *(const float4*)(x + idx + 4);
    short8 o;
    o[0] = (short)f2bf(a.x); o[1] = (short)f2bf(a.y);
    o[2] = (short)f2bf(a.z); o[3] = (short)f2bf(a.w);
    o[4] = (short)f2bf(b.x); o[5] = (short)f2bf(b.y);
    o[6] = (short)f2bf(b.z); o[7] = (short)f2bf(b.w);
    *(short8*)(xb + idx) = o;
}

// ---------------- transpose W fp32 [d][e] -> bf16 Wt [e][d], 3 weights -------
__global__ __launch_bounds__(256) void k_transpose_w(const float* __restrict__ W0,
                                                     const float* __restrict__ W1,
                                                     const float* __restrict__ W2,
                                                     ushort_t* __restrict__ Wt) {
    const float* W = (blockIdx.z == 0) ? W0 : (blockIdx.z == 1) ? W1 : W2;
    ushort_t* out = Wt + (size_t)blockIdx.z * 1024 * 1024;
    __shared__ float tile[32][33];
    int tx = threadIdx.x, ty = threadIdx.y;            // 32 x 8
    int d0 = blockIdx.y * 32, e0 = blockIdx.x * 32;
#pragma unroll
    for (int i = 0; i < 32; i += 8)
        tile[ty + i][tx] = W[(size_t)(d0 + ty + i) * 1024 + e0 + tx];
    __syncthreads();
#pragma unroll
    for (int i = 0; i < 32; i += 8)
        out[(size_t)(e0 + ty + i) * 1024 + d0 + tx] = f2bf(tile[tx][ty + i]);
}

// ---------------- transpose V bf16 [b][j][e] -> Vt [b][e][j] ----------------
__global__ __launch_bounds__(256) void k_transpose_v(const ushort_t* __restrict__ V,
                                                     ushort_t* __restrict__ Vt) {
    int b = blockIdx.z;
    const ushort_t* in = V + (size_t)b * 2048 * 1024;
    ushort_t* out = Vt + (size_t)b * 1024 * 2048;
    __shared__ ushort_t tile[32][33];
    int tx = threadIdx.x, ty = threadIdx.y;            // 32 x 8
    int e0 = blockIdx.x * 32, j0 = blockIdx.y * 32;
#pragma unroll
    for (int i = 0; i < 32; i += 8)
        tile[ty + i][tx] = in[(size_t)(j0 + ty + i) * 1024 + e0 + tx];
    __syncthreads();
#pragma unroll
    for (int i = 0; i < 32; i += 8)
        out[(size_t)(e0 + ty + i) * 2048 + j0 + tx] = tile[tx][ty + i];
}

// ---------------- proj GEMM: 256x256 tile, BK=64, 8 waves (2x4) --------------
// C = xb[8192][1024] * Wt[3072][1024]^T -> QKV[z][8192][1024] (n = z*1024+col)
// Per wave: 128x64 output, acc[8][4]. Frags: a[4][2] (reloaded), b[4][2].
// Reads/MFMA = 24/64 = 0.375. LDS 128KB (2 dbuf x 32KB A + 32KB B).
// Swizzle: LDS elem group ce = c ^ ((row&7)<<3); stage pre-swizzles global src.
// Schedule per K-tile (4 phases, 16 MFMA each):
//   P0: issue stageA(T+1); read b[4][2] + a[0..3][2]; MFMA m0-3 x n0-1
//   P1: issue stageB(T+1); MFMA m0-3 x n2-3
//   P2: read a[4..7][2];   MFMA m4-7 x n0-1
//   P3:                    MFMA m4-7 x n2-3 ; vmcnt(0) ; barrier
// Only the 8 stage ops are in flight at the boundary wait (~3 phases of cover).
__global__ __launch_bounds__(512) void k_proj256(const ushort_t* __restrict__ X,
                                                 const ushort_t* __restrict__ Wt,
                                                 ushort_t* __restrict__ QKV) {
    const int bm = blockIdx.x, bn = blockIdx.y;

    __shared__ ushort_t Asm[2][16384];   // [dbuf][256 rows x 64 k]  64KB
    __shared__ ushort_t Bsm[2][16384];   // 64KB

    const int tid = threadIdx.x;
    const int l = tid & 63, w = tid >> 6;
    const int wrow = w >> 2, wcol = w & 3;       // 2 x 4 wave grid
    const int lr = l & 15, lg = l >> 4;
    const int cx = (lr & 7) << 3;                // read-side XOR (elem units)

    // staging: thread covers rows srow + {0,64,128,192}, pre-swizzled col group
    const int srow = tid >> 3;                               // 0..63
    const int scol = (((tid & 7) ^ (srow & 7)) << 3);        // 0..56
    const ushort_t* Ag = X  + (size_t)(bm * 256 + srow) * 1024 + scol;
    const ushort_t* Bg = Wt + (size_t)(bn * 256 + srow) * 1024 + scol;

    f32x4 zero = {0.f, 0.f, 0.f, 0.f};
    f32x4 acc[8][4];
#pragma unroll
    for (int m = 0; m < 8; ++m)
#pragma unroll
        for (int n = 0; n < 4; ++n) acc[m][n] = zero;

    auto stageA = [&](int T) {
        ushort_t* dst = &Asm[T & 1][tid * 8];
        const ushort_t* src = Ag + T * 64;
#pragma unroll
        for (int c = 0; c < 4; ++c)
            gload16(src + (size_t)(c * 64) * 1024, dst + c * 4096);
    };
    auto stageB = [&](int T) {
        ushort_t* dst = &Bsm[T & 1][tid * 8];
        const ushort_t* src = Bg + T * 64;
#pragma unroll
        for (int c = 0; c < 4; ++c)
            gload16(src + (size_t)(c * 64) * 1024, dst + c * 4096);
    };

    // prologue: tile 0
    stageA(0); stageB(0);
    asm volatile("s_waitcnt vmcnt(0)" ::: "memory");
    __builtin_amdgcn_s_barrier();

    for (int T = 0; T < 16; ++T) {
        const ushort_t* As = Asm[T & 1];
        const ushort_t* Bs = Bsm[T & 1];
        short8 a[4][2], b[4][2];

        // ---- P0 ----
        if (T + 1 < 16) stageA(T + 1);
#pragma unroll
        for (int nf = 0; nf < 4; ++nf)
#pragma unroll
            for (int kh = 0; kh < 2; ++kh)
                b[nf][kh] = *(const short8*)&Bs[(wcol * 64 + nf * 16 + lr) * 64 + ((kh * 32 + lg * 8) ^ cx)];
#pragma unroll
        for (int mf = 0; mf < 4; ++mf)
#pragma unroll
            for (int kh = 0; kh < 2; ++kh)
                a[mf][kh] = *(const short8*)&As[(wrow * 128 + mf * 16 + lr) * 64 + ((kh * 32 + lg * 8) ^ cx)];
        __builtin_amdgcn_s_setprio(1);
#pragma unroll
        for (int mf = 0; mf < 4; ++mf)
#pragma unroll
            for (int nf = 0; nf < 2; ++nf)
#pragma unroll
                for (int kh = 0; kh < 2; ++kh)
                    acc[mf][nf] = __builtin_amdgcn_mfma_f32_16x16x32_bf16(a[mf][kh], b[nf][kh], acc[mf][nf], 0, 0, 0);
        __builtin_amdgcn_s_setprio(0);
        __builtin_amdgcn_s_barrier();

        // ---- P1 ----
        if (T + 1 < 16) stageB(T + 1);
        __builtin_amdgcn_s_setprio(1);
#pragma unroll
        for (int mf = 0; mf < 4; ++mf)
#pragma unroll
            for (int nf = 2; nf < 4; ++nf)
#pragma unroll
                for (int kh = 0; kh < 2; ++kh)
                    acc[mf][nf] = __builtin_amdgcn_mfma_f32_16x16x32_bf16(a[mf][kh], b[nf][kh], acc[mf][nf], 0, 0, 0);
        __builtin_amdgcn_s_setprio(0);
        __builtin_amdgcn_s_barrier();

        // ---- P2 ----
#pragma unroll
        for (int mf = 0; mf < 4; ++mf)
#pragma unroll
            for (int kh = 0; kh < 2; ++kh)
                a[mf][kh] = *(const short8*)&As[(wrow * 128 + 64 + mf * 16 + lr) * 64 + ((kh * 32 + lg * 8) ^ cx)];
        __builtin_amdgcn_s_setprio(1);
#pragma unroll
        for (int mf = 0; mf < 4; ++mf)
#pragma unroll
            for (int nf = 0; nf < 2; ++nf)
#pragma unroll
                for (int kh = 0; kh < 2; ++kh)
                    acc[4 + mf][nf] = __builtin_amdgcn_mfma_f32_16x16x32_bf16(a[mf][kh], b[nf][kh], acc[4 + mf][nf], 0, 0, 0);
        __builtin_amdgcn_s_setprio(0);
        __builtin_amdgcn_s_barrier();

        // ---- P3 ----
        __builtin_amdgcn_s_setprio(1);
#pragma unroll
        for (int mf = 0; mf < 4; ++mf)
#pragma unroll
            for (int nf = 2; nf < 4; ++nf)
#pragma unroll
                for (int kh = 0; kh < 2; ++kh)
                    acc[4 + mf][nf] = __builtin_amdgcn_mfma_f32_16x16x32_bf16(a[mf][kh], b[nf][kh], acc[4 + mf][nf], 0, 0, 0);
        __builtin_amdgcn_s_setprio(0);
        asm volatile("s_waitcnt vmcnt(0)" ::: "memory");   // next tile staged
        __builtin_amdgcn_s_barrier();
    }

    // epilogue: n = bn*256 + wcol*64 + nf*16 + lr -> z = bn>>2, col within z
    ushort_t* C = QKV + (size_t)(bn >> 2) * 8388608;
    const int colbase = (bn & 3) * 256 + wcol * 64;
    const int rb = lg * 4;
#pragma unroll
    for (int m = 0; m < 8; ++m)
#pragma unroll
        for (int nf = 0; nf < 4; ++nf) {
            int col = colbase + nf * 16 + lr;
#pragma unroll
            for (int r = 0; r < 4; ++r) {
                int grow = bm * 256 + wrow * 128 + m * 16 + rb + r;
                C[(size_t)grow * 1024 + col] = f2bf(acc[m][nf][r]);
            }
        }
}

// ---------------- GEMM (m97 128x128): C = A * B^T ----------------
// MODE 1: qk    triangular grid (136,1,4); C=scores fp32 (*1/32, causal)
// MODE 2: pv    A=P bf16 lda=4096; B=Vt; C=out fp32, K-range causal, bm remap
template <int MODE>
__global__ __launch_bounds__(256) void k_gemm(const ushort_t* __restrict__ Abase,
                                              const ushort_t* __restrict__ Bbase,
                                              void* __restrict__ Cbase) {
    const int bz = blockIdx.z;
    int bm, bn;
    const ushort_t* A;
    const ushort_t* B;
    int lda, ldb, nk;
    if constexpr (MODE == 1) {
        int x = blockIdx.x;
        bm = (int)((sqrtf(8.f * x + 1.f) - 1.f) * 0.5f);
        while ((bm + 1) * (bm + 2) / 2 <= x) ++bm;
        while (bm * (bm + 1) / 2 > x) --bm;
        bn = x - bm * (bm + 1) / 2;
        A = Abase + (size_t)bz * 2048 * 1024; lda = 1024;
        B = Bbase + (size_t)bz * 2048 * 1024; ldb = 1024;
        nk = 32;
    } else {
        int xr = blockIdx.x;                       // heavy/light interleave
        bm = (xr & 1) ? (15 - (xr >> 1)) : (xr >> 1);
        bn = blockIdx.y;
        A = Abase + (size_t)bz * 2048 * 4096; lda = 4096;
        B = Bbase + (size_t)bz * 1024 * 2048; ldb = 2048;
        nk = (bm + 1) * 4;  // causal K truncation: j <= bm*128+127
    }

    __shared__ ushort_t As[128 * 32];   // linear (gload_lds dest)
    __shared__ ushort_t Bs[128 * 32];

    const int tid = threadIdx.x;
    const int l = tid & 63, wid = tid >> 6;
    const int wr = (wid >> 1) * 64, wc = (wid & 1) * 64;
    const int lr = l & 15, kc = (l >> 4) * 8;

    const int srow = tid >> 2, skb = (tid & 3) * 8;
    const ushort_t* ag = A + (size_t)(bm * 128 + srow) * lda + skb;
    const ushort_t* bg = B + (size_t)(bn * 128 + srow) * ldb + skb;
    const size_t a64 = (size_t)64 * lda, b64 = (size_t)64 * ldb;
    ushort_t* al = As + tid * 8;
    ushort_t* bl = Bs + tid * 8;

    f32x4 zero = {0.f, 0.f, 0.f, 0.f};
    f32x4 acc[4][4];
#pragma unroll
    for (int m = 0; m < 4; ++m)
#pragma unroll
        for (int n = 0; n < 4; ++n) acc[m][n] = zero;

    for (int ks = 0; ks < nk; ++ks) {
        __syncthreads();
        gload16(ag, al);
        gload16(ag + a64, al + 2048);
        gload16(bg, bl);
        gload16(bg + b64, bl + 2048);
        ag += 32; bg += 32;
        __syncthreads();

        short8 a[4], b[4];
#pragma unroll
        for (int m = 0; m < 4; ++m)
            a[m] = *(const short8*)&As[(wr + m * 16 + lr) * 32 + kc];
#pragma unroll
        for (int n = 0; n < 4; ++n)
            b[n] = *(const short8*)&Bs[(wc + n * 16 + lr) * 32 + kc];
#pragma unroll
        for (int m = 0; m < 4; ++m)
#pragma unroll
            for (int n = 0; n < 4; ++n)
                acc[m][n] = __builtin_amdgcn_mfma_f32_16x16x32_bf16(a[m], b[n], acc[m][n], 0, 0, 0);
    }

    const int rbase = (l >> 4) * 4;
    const int cbase = l & 15;
#pragma unroll
    for (int m = 0; m < 4; ++m) {
#pragma unroll
        for (int n = 0; n < 4; ++n) {
            int row0 = wr + m * 16 + rbase;
            int col = wc + n * 16 + cbase;
            int gcol = bn * 128 + col;
#pragma unroll
            for (int r = 0; r < 4; ++r) {
                int grow = bm * 128 + row0 + r;
                float v = acc[m][n][r];
                if constexpr (MODE == 1) {
                    float* C = (float*)Cbase + (size_t)bz * 2048 * 2048;
                    if (gcol <= grow) C[(size_t)grow * 2048 + gcol] = v * 0.03125f;
                } else {
                    float* C = (float*)Cbase + (size_t)bz * 2048 * 1024;
                    C[(size_t)grow * 1024 + gcol] = v;
                }
            }
        }
    }
}

// ---------------- row softmax: fp32 scores row -> normalized bf16 P in place -
// Truncated to the 128-aligned causal limit (PV reads cols < (bm+1)*128 only).
__global__ __launch_bounds__(256) void k_softmax(float* __restrict__ scores) {
    const int t = blockIdx.x;        // global row 0..8191
    const int i = t & 2047;          // row within batch (causal limit)
    const int limit = ((i >> 7) + 1) << 7;   // 128..2048
    float* row = scores + (size_t)t * 2048;
    const int tid = threadIdx.x;
    const int j0 = tid * 8;
    const bool active = (j0 < limit);

    float v[8];
    if (active) {
        float4 f0 = *(const float4*)(row + j0);
        float4 f1 = *(const float4*)(row + j0 + 4);
        v[0] = f0.x; v[1] = f0.y; v[2] = f0.z; v[3] = f0.w;
        v[4] = f1.x; v[5] = f1.y; v[6] = f1.z; v[7] = f1.w;
    }

    float m = -3.0e38f;
    if (active) {
#pragma unroll
        for (int e = 0; e < 8; ++e)
            if (j0 + e <= i) m = fmaxf(m, v[e]);
    }
#pragma unroll
    for (int off = 32; off > 0; off >>= 1) m = fmaxf(m, __shfl_down(m, off, 64));

    __shared__ float redm[4];
    __shared__ float reds[4];
    const int lane = tid & 63, wid = tid >> 6;
    if (lane == 0) redm[wid] = m;
    __syncthreads();
    m = fmaxf(fmaxf(redm[0], redm[1]), fmaxf(redm[2], redm[3]));

    float p[8];
    float s = 0.f;
    if (active) {
#pragma unroll
        for (int e = 0; e < 8; ++e) {
            p[e] = (j0 + e <= i) ? __expf(v[e] - m) : 0.f;
            s += p[e];
        }
    }
#pragma unroll
    for (int off = 32; off > 0; off >>= 1) s += __shfl_down(s, off, 64);
    if (lane == 0) reds[wid] = s;
    __syncthreads();
    s = reds[0] + reds[1] + reds[2] + reds[3];
    float inv = 1.f / s;

    if (active) {
        short8 o;
#pragma unroll
        for (int e = 0; e < 8; ++e) o[e] = (short)f2bf(p[e] * inv);
        *(short8*)((ushort_t*)row + j0) = o;   // bf16 row, stride 4096 elems
    }
}

extern "C" void kernel_launch(void* const* d_in, const int* in_sizes, int n_in,
                              void* d_out, int out_size, void* d_ws, size_t ws_size,
                              hipStream_t stream) {
    const float* x  = (const float*)d_in[0];
    const float* Wq = (const float*)d_in[1];
    const float* Wk = (const float*)d_in[2];
    const float* Wv = (const float*)d_in[3];

    char* ws = (char*)d_ws;
    ushort_t* xb     = (ushort_t*)(ws);                 // 16 MB
    ushort_t* Wt     = (ushort_t*)(ws + 16777216);      // 6 MB  [3][1024][1024] == [3072][1024]
    ushort_t* QKV    = (ushort_t*)(ws + 23068672);      // 48 MB [3][8192][1024]
    ushort_t* Vt     = (ushort_t*)(ws + 73400320);      // 16 MB [4][1024][2048]
    float*    scores = (float*)   (ws + 90177536);      // 64 MB [4][2048][2048] fp32 / P bf16

    ushort_t* Q = QKV;
    ushort_t* K = QKV + (size_t)8192 * 1024;
    ushort_t* V = QKV + (size_t)2 * 8192 * 1024;

    k_convert_x<<<4096, 256, 0, stream>>>(x, xb);
    k_transpose_w<<<dim3(32, 32, 3), dim3(32, 8), 0, stream>>>(Wq, Wk, Wv, Wt);
    k_proj256<<<dim3(32, 12), 512, 0, stream>>>(xb, Wt, QKV);
    k_transpose_v<<<dim3(32, 64, 4), dim3(32, 8), 0, stream>>>(V, Vt);
    k_gemm<1><<<dim3(136, 1, 4), 256, 0, stream>>>(Q, K, scores);
    k_softmax<<<8192, 256, 0, stream>>>(scores);
    k_gemm<2><<<dim3(16, 8, 4), 256, 0, stream>>>((const ushort_t*)scores, Vt, (float*)d_out);
}

// Round 5
// 200.250 us; speedup vs baseline: 1.0754x; 1.0199x over previous
//
#include <hip/hip_runtime.h>
#include <hip/hip_bf16.h>

typedef __attribute__((ext_vector_type(8))) short short8;
typedef __attribute__((ext_vector_type(4))) float f32x4;
typedef unsigned short ushort_t;

__device__ __forceinline__ ushort_t f2bf(float f) {
    union { __hip_bfloat16 h; ushort_t u; } c;
    c.h = __float2bfloat16(f);
    return c.u;
}

__device__ __forceinline__ void gload16(const ushort_t* g, ushort_t* l) {
    __builtin_amdgcn_global_load_lds(
        (const __attribute__((address_space(1))) void*)g,
        (__attribute__((address_space(3))) void*)l, 16, 0, 0);
}

#define FENCE asm volatile("" ::: "memory")

// ---------------- convert x fp32 -> bf16 ----------------
__global__ __launch_bounds__(256) void k_convert_x(const float* __restrict__ x,
                                                   ushort_t* __restrict__ xb) {
    size_t idx = ((size_t)blockIdx.x * 256 + threadIdx.x) * 8;
    float4 a = *(const float4*)(x + idx);
    float4 b = *(const float4*)(x + idx + 4);
    short8 o;
    o[0] = (short)f2bf(a.x); o[1] = (short)f2bf(a.y);
    o[2] = (short)f2bf(a.z); o[3] = (short)f2bf(a.w);
    o[4] = (short)f2bf(b.x); o[5] = (short)f2bf(b.y);
    o[6] = (short)f2bf(b.z); o[7] = (short)f2bf(b.w);
    *(short8*)(xb + idx) = o;
}

// ---------------- transpose W fp32 [d][e] -> bf16 Wt [e][d], 3 weights -------
__global__ __launch_bounds__(256) void k_transpose_w(const float* __restrict__ W0,
                                                     const float* __restrict__ W1,
                                                     const float* __restrict__ W2,
                                                     ushort_t* __restrict__ Wt) {
    const float* W = (blockIdx.z == 0) ? W0 : (blockIdx.z == 1) ? W1 : W2;
    ushort_t* out = Wt + (size_t)blockIdx.z * 1024 * 1024;
    __shared__ float tile[32][33];
    int tx = threadIdx.x, ty = threadIdx.y;            // 32 x 8
    int d0 = blockIdx.y * 32, e0 = blockIdx.x * 32;
#pragma unroll
    for (int i = 0; i < 32; i += 8)
        tile[ty + i][tx] = W[(size_t)(d0 + ty + i) * 1024 + e0 + tx];
    __syncthreads();
#pragma unroll
    for (int i = 0; i < 32; i += 8)
        out[(size_t)(e0 + ty + i) * 1024 + d0 + tx] = f2bf(tile[tx][ty + i]);
}

// ---------------- transpose V bf16 [b][j][e] -> Vt [b][e][j] ----------------
__global__ __launch_bounds__(256) void k_transpose_v(const ushort_t* __restrict__ V,
                                                     ushort_t* __restrict__ Vt) {
    int b = blockIdx.z;
    const ushort_t* in = V + (size_t)b * 2048 * 1024;
    ushort_t* out = Vt + (size_t)b * 1024 * 2048;
    __shared__ ushort_t tile[32][33];
    int tx = threadIdx.x, ty = threadIdx.y;            // 32 x 8
    int e0 = blockIdx.x * 32, j0 = blockIdx.y * 32;
#pragma unroll
    for (int i = 0; i < 32; i += 8)
        tile[ty + i][tx] = in[(size_t)(j0 + ty + i) * 1024 + e0 + tx];
    __syncthreads();
#pragma unroll
    for (int i = 0; i < 32; i += 8)
        out[(size_t)(e0 + ty + i) * 2048 + j0 + tx] = tile[tx][ty + i];
}

// ---------------- proj GEMM: m201 8-phase port. 256x256, BK=64, 8 waves -----
// C = xb[8192][1024] * Wt[3072][1024]^T -> QKV[z][8192][1024]
// LDS: [dbuf][half][128x64] for A and B (128 KiB). Half h of tile T: rows
// hf*128..+127. Stage order {A0,B0,A1,B1}/tile, one half per phase, lead=5:
//   sub0: stage B0(t+1); sub1: A1(t+1); sub2: B1(t+1); sub3: A0(t+2).
// Counted waits: vmcnt(2) at each group end (t<=13), vmcnt(0) at t=14.
// Ledger: WAR-safe (stage of tile t+2 half issues at sub3 of t, after all
// tile-t reads completed via sub-phase barriers); visibility-safe (vmcnt(2)
// leaves only the sub3-issued half in flight, which belongs to tile t+2).
// Swizzle (both sides): read col ^= (row&7)<<3; stage src col pre-swizzled.
__global__ __launch_bounds__(512) void k_proj256(const ushort_t* __restrict__ X,
                                                 const ushort_t* __restrict__ Wt,
                                                 ushort_t* __restrict__ QKV) {
    const int bm = blockIdx.x, bn = blockIdx.y;

    __shared__ ushort_t Asm[2][2][8192];   // [dbuf][half][128*64] 64KB
    __shared__ ushort_t Bsm[2][2][8192];   // 64KB

    const int tid = threadIdx.x;
    const int l = tid & 63, w = tid >> 6;
    const int wrow = w >> 2, wcol = w & 3;       // 2 x 4 wave grid
    const int lr = l & 15, lg = l >> 4;
    const int cx = (lr & 7) << 3;                // read-side XOR (elems)

    // staging: thread covers rows srow, srow+64 of a 128-row half
    const int srow = tid >> 3;                               // 0..63
    const int scol = (((tid & 7) ^ (srow & 7)) << 3);        // pre-swizzled
    const ushort_t* Ags = X  + (size_t)(bm * 256 + srow) * 1024 + scol;
    const ushort_t* Bgs = Wt + (size_t)(bn * 256 + srow) * 1024 + scol;

    auto stageA = [&](int T, int hf) {
        const ushort_t* src = Ags + (size_t)(hf * 128) * 1024 + T * 64;
        ushort_t* dst = &Asm[T & 1][hf][tid * 8];
        gload16(src, dst);
        gload16(src + (size_t)64 * 1024, dst + 4096);
    };
    auto stageB = [&](int T, int hf) {
        const ushort_t* src = Bgs + (size_t)(hf * 128) * 1024 + T * 64;
        ushort_t* dst = &Bsm[T & 1][hf][tid * 8];
        gload16(src, dst);
        gload16(src + (size_t)64 * 1024, dst + 4096);
    };

    f32x4 zero = {0.f, 0.f, 0.f, 0.f};
    f32x4 acc[8][4];
#pragma unroll
    for (int m = 0; m < 8; ++m)
#pragma unroll
        for (int n = 0; n < 4; ++n) acc[m][n] = zero;

    // prologue: halves A0,B0,A1,B1 of tile0 + A0 of tile1
    stageA(0, 0); stageB(0, 0); stageA(0, 1); stageB(0, 1); stageA(1, 0);
    asm volatile("s_waitcnt vmcnt(2)" ::: "memory");
    __builtin_amdgcn_s_barrier();

    const int brow = (wcol & 1) * 64;

#pragma unroll 2
    for (int t = 0; t < 16; ++t) {
        const int db = t & 1;
        const ushort_t* Ah = Asm[db][wrow];
        const ushort_t* Bh = Bsm[db][wcol >> 1];
        short8 a[4][2], b0[2][2], b1[2][2];

        // ---- sub0: read a(mq0) + b0; stage B0(t+1); MFMA q(0,0) ----
#pragma unroll
        for (int mf = 0; mf < 4; ++mf)
#pragma unroll
            for (int kh = 0; kh < 2; ++kh)
                a[mf][kh] = *(const short8*)&Ah[(mf * 16 + lr) * 64 + ((kh * 32 + lg * 8) ^ cx)];
#pragma unroll
        for (int nf = 0; nf < 2; ++nf)
#pragma unroll
            for (int kh = 0; kh < 2; ++kh)
                b0[nf][kh] = *(const short8*)&Bh[(brow + nf * 16 + lr) * 64 + ((kh * 32 + lg * 8) ^ cx)];
        if (t < 15) stageB(t + 1, 0);
        FENCE; __builtin_amdgcn_s_barrier();
        asm volatile("s_waitcnt lgkmcnt(0)" ::: "memory");
        __builtin_amdgcn_sched_barrier(0);
        __builtin_amdgcn_s_setprio(1);
#pragma unroll
        for (int mf = 0; mf < 4; ++mf)
#pragma unroll
            for (int nf = 0; nf < 2; ++nf)
#pragma unroll
                for (int kh = 0; kh < 2; ++kh)
                    acc[mf][nf] = __builtin_amdgcn_mfma_f32_16x16x32_bf16(a[mf][kh], b0[nf][kh], acc[mf][nf], 0, 0, 0);
        __builtin_amdgcn_s_setprio(0);
        FENCE; __builtin_amdgcn_s_barrier(); FENCE;

        // ---- sub1: read b1; stage A1(t+1); MFMA q(0,1) ----
#pragma unroll
        for (int nf = 0; nf < 2; ++nf)
#pragma unroll
            for (int kh = 0; kh < 2; ++kh)
                b1[nf][kh] = *(const short8*)&Bh[(brow + (nf + 2) * 16 + lr) * 64 + ((kh * 32 + lg * 8) ^ cx)];
        if (t < 15) stageA(t + 1, 1);
        FENCE; __builtin_amdgcn_s_barrier();
        asm volatile("s_waitcnt lgkmcnt(0)" ::: "memory");
        __builtin_amdgcn_sched_barrier(0);
        __builtin_amdgcn_s_setprio(1);
#pragma unroll
        for (int mf = 0; mf < 4; ++mf)
#pragma unroll
            for (int nf = 0; nf < 2; ++nf)
#pragma unroll
                for (int kh = 0; kh < 2; ++kh)
                    acc[mf][nf + 2] = __builtin_amdgcn_mfma_f32_16x16x32_bf16(a[mf][kh], b1[nf][kh], acc[mf][nf + 2], 0, 0, 0);
        __builtin_amdgcn_s_setprio(0);
        FENCE; __builtin_amdgcn_s_barrier(); FENCE;

        // ---- sub2: read a(mq1); stage B1(t+1); MFMA q(1,0) ----
#pragma unroll
        for (int mf = 0; mf < 4; ++mf)
#pragma unroll
            for (int kh = 0; kh < 2; ++kh)
                a[mf][kh] = *(const short8*)&Ah[(64 + mf * 16 + lr) * 64 + ((kh * 32 + lg * 8) ^ cx)];
        if (t < 15) stageB(t + 1, 1);
        FENCE; __builtin_amdgcn_s_barrier();
        asm volatile("s_waitcnt lgkmcnt(0)" ::: "memory");
        __builtin_amdgcn_sched_barrier(0);
        __builtin_amdgcn_s_setprio(1);
#pragma unroll
        for (int mf = 0; mf < 4; ++mf)
#pragma unroll
            for (int nf = 0; nf < 2; ++nf)
#pragma unroll
                for (int kh = 0; kh < 2; ++kh)
                    acc[4 + mf][nf] = __builtin_amdgcn_mfma_f32_16x16x32_bf16(a[mf][kh], b0[nf][kh], acc[4 + mf][nf], 0, 0, 0);
        __builtin_amdgcn_s_setprio(0);
        FENCE; __builtin_amdgcn_s_barrier(); FENCE;

        // ---- sub3: stage A0(t+2); MFMA q(1,1); counted vmcnt ----
        if (t < 14) stageA(t + 2, 0);
        FENCE; __builtin_amdgcn_s_barrier();
        asm volatile("s_waitcnt lgkmcnt(0)" ::: "memory");
        __builtin_amdgcn_sched_barrier(0);
        __builtin_amdgcn_s_setprio(1);
#pragma unroll
        for (int mf = 0; mf < 4; ++mf)
#pragma unroll
            for (int nf = 0; nf < 2; ++nf)
#pragma unroll
                for (int kh = 0; kh < 2; ++kh)
                    acc[4 + mf][nf + 2] = __builtin_amdgcn_mfma_f32_16x16x32_bf16(a[mf][kh], b1[nf][kh], acc[4 + mf][nf + 2], 0, 0, 0);
        __builtin_amdgcn_s_setprio(0);
        if (t < 14) {
            asm volatile("s_waitcnt vmcnt(2)" ::: "memory");
        } else if (t == 14) {
            asm volatile("s_waitcnt vmcnt(0)" ::: "memory");
        }
        FENCE; __builtin_amdgcn_s_barrier(); FENCE;
    }

    // epilogue: n = bn*256 + wcol*64 + nf*16 + lr -> z = bn>>2
    ushort_t* C = QKV + (size_t)(bn >> 2) * 8388608;
    const int colbase = (bn & 3) * 256 + wcol * 64;
    const int rb = lg * 4;
#pragma unroll
    for (int m = 0; m < 8; ++m)
#pragma unroll
        for (int nf = 0; nf < 4; ++nf) {
            int col = colbase + nf * 16 + lr;
#pragma unroll
            for (int r = 0; r < 4; ++r) {
                int grow = bm * 256 + wrow * 128 + m * 16 + rb + r;
                C[(size_t)grow * 1024 + col] = f2bf(acc[m][nf][r]);
            }
        }
}

// ---------------- GEMM (m97 128x128): C = A * B^T ----------------
// MODE 1: qk    triangular grid (136,1,4); C=scores fp32 (*1/32, causal)
// MODE 2: pv    A=P bf16 lda=4096; B=Vt; C=out fp32, K-range causal, bm remap
template <int MODE>
__global__ __launch_bounds__(256) void k_gemm(const ushort_t* __restrict__ Abase,
                                              const ushort_t* __restrict__ Bbase,
                                              void* __restrict__ Cbase) {
    const int bz = blockIdx.z;
    int bm, bn;
    const ushort_t* A;
    const ushort_t* B;
    int lda, ldb, nk;
    if constexpr (MODE == 1) {
        int x = blockIdx.x;
        bm = (int)((sqrtf(8.f * x + 1.f) - 1.f) * 0.5f);
        while ((bm + 1) * (bm + 2) / 2 <= x) ++bm;
        while (bm * (bm + 1) / 2 > x) --bm;
        bn = x - bm * (bm + 1) / 2;
        A = Abase + (size_t)bz * 2048 * 1024; lda = 1024;
        B = Bbase + (size_t)bz * 2048 * 1024; ldb = 1024;
        nk = 32;
    } else {
        int xr = blockIdx.x;                       // heavy/light interleave
        bm = (xr & 1) ? (15 - (xr >> 1)) : (xr >> 1);
        bn = blockIdx.y;
        A = Abase + (size_t)bz * 2048 * 4096; lda = 4096;
        B = Bbase + (size_t)bz * 1024 * 2048; ldb = 2048;
        nk = (bm + 1) * 4;  // causal K truncation: j <= bm*128+127
    }

    __shared__ ushort_t As[128 * 32];   // linear (gload_lds dest)
    __shared__ ushort_t Bs[128 * 32];

    const int tid = threadIdx.x;
    const int l = tid & 63, wid = tid >> 6;
    const int wr = (wid >> 1) * 64, wc = (wid & 1) * 64;
    const int lr = l & 15, kc = (l >> 4) * 8;

    const int srow = tid >> 2, skb = (tid & 3) * 8;
    const ushort_t* ag = A + (size_t)(bm * 128 + srow) * lda + skb;
    const ushort_t* bg = B + (size_t)(bn * 128 + srow) * ldb + skb;
    const size_t a64 = (size_t)64 * lda, b64 = (size_t)64 * ldb;
    ushort_t* al = As + tid * 8;
    ushort_t* bl = Bs + tid * 8;

    f32x4 zero = {0.f, 0.f, 0.f, 0.f};
    f32x4 acc[4][4];
#pragma unroll
    for (int m = 0; m < 4; ++m)
#pragma unroll
        for (int n = 0; n < 4; ++n) acc[m][n] = zero;

    for (int ks = 0; ks < nk; ++ks) {
        __syncthreads();
        gload16(ag, al);
        gload16(ag + a64, al + 2048);
        gload16(bg, bl);
        gload16(bg + b64, bl + 2048);
        ag += 32; bg += 32;
        __syncthreads();

        short8 a[4], b[4];
#pragma unroll
        for (int m = 0; m < 4; ++m)
            a[m] = *(const short8*)&As[(wr + m * 16 + lr) * 32 + kc];
#pragma unroll
        for (int n = 0; n < 4; ++n)
            b[n] = *(const short8*)&Bs[(wc + n * 16 + lr) * 32 + kc];
#pragma unroll
        for (int m = 0; m < 4; ++m)
#pragma unroll
            for (int n = 0; n < 4; ++n)
                acc[m][n] = __builtin_amdgcn_mfma_f32_16x16x32_bf16(a[m], b[n], acc[m][n], 0, 0, 0);
    }

    const int rbase = (l >> 4) * 4;
    const int cbase = l & 15;
#pragma unroll
    for (int m = 0; m < 4; ++m) {
#pragma unroll
        for (int n = 0; n < 4; ++n) {
            int row0 = wr + m * 16 + rbase;
            int col = wc + n * 16 + cbase;
            int gcol = bn * 128 + col;
#pragma unroll
            for (int r = 0; r < 4; ++r) {
                int grow = bm * 128 + row0 + r;
                float v = acc[m][n][r];
                if constexpr (MODE == 1) {
                    float* C = (float*)Cbase + (size_t)bz * 2048 * 2048;
                    if (gcol <= grow) C[(size_t)grow * 2048 + gcol] = v * 0.03125f;
                } else {
                    float* C = (float*)Cbase + (size_t)bz * 2048 * 1024;
                    C[(size_t)grow * 1024 + gcol] = v;
                }
            }
        }
    }
}

// ---------------- row softmax: fp32 scores row -> normalized bf16 P in place -
// Truncated to the 128-aligned causal limit (PV reads cols < (bm+1)*128 only).
__global__ __launch_bounds__(256) void k_softmax(float* __restrict__ scores) {
    const int t = blockIdx.x;        // global row 0..8191
    const int i = t & 2047;          // row within batch (causal limit)
    const int limit = ((i >> 7) + 1) << 7;   // 128..2048
    float* row = scores + (size_t)t * 2048;
    const int tid = threadIdx.x;
    const int j0 = tid * 8;
    const bool active = (j0 < limit);

    float v[8];
    if (active) {
        float4 f0 = *(const float4*)(row + j0);
        float4 f1 = *(const float4*)(row + j0 + 4);
        v[0] = f0.x; v[1] = f0.y; v[2] = f0.z; v[3] = f0.w;
        v[4] = f1.x; v[5] = f1.y; v[6] = f1.z; v[7] = f1.w;
    }

    float m = -3.0e38f;
    if (active) {
#pragma unroll
        for (int e = 0; e < 8; ++e)
            if (j0 + e <= i) m = fmaxf(m, v[e]);
    }
#pragma unroll
    for (int off = 32; off > 0; off >>= 1) m = fmaxf(m, __shfl_down(m, off, 64));

    __shared__ float redm[4];
    __shared__ float reds[4];
    const int lane = tid & 63, wid = tid >> 6;
    if (lane == 0) redm[wid] = m;
    __syncthreads();
    m = fmaxf(fmaxf(redm[0], redm[1]), fmaxf(redm[2], redm[3]));

    float p[8];
    float s = 0.f;
    if (active) {
#pragma unroll
        for (int e = 0; e < 8; ++e) {
            p[e] = (j0 + e <= i) ? __expf(v[e] - m) : 0.f;
            s += p[e];
        }
    }
#pragma unroll
    for (int off = 32; off > 0; off >>= 1) s += __shfl_down(s, off, 64);
    if (lane == 0) reds[wid] = s;
    __syncthreads();
    s = reds[0] + reds[1] + reds[2] + reds[3];
    float inv = 1.f / s;

    if (active) {
        short8 o;
#pragma unroll
        for (int e = 0; e < 8; ++e) o[e] = (short)f2bf(p[e] * inv);
        *(short8*)((ushort_t*)row + j0) = o;   // bf16 row, stride 4096 elems
    }
}

extern "C" void kernel_launch(void* const* d_in, const int* in_sizes, int n_in,
                              void* d_out, int out_size, void* d_ws, size_t ws_size,
                              hipStream_t stream) {
    const float* x  = (const float*)d_in[0];
    const float* Wq = (const float*)d_in[1];
    const float* Wk = (const float*)d_in[2];
    const float* Wv = (const float*)d_in[3];

    char* ws = (char*)d_ws;
    ushort_t* xb     = (ushort_t*)(ws);                 // 16 MB
    ushort_t* Wt     = (ushort_t*)(ws + 16777216);      // 6 MB  [3][1024][1024] == [3072][1024]
    ushort_t* QKV    = (ushort_t*)(ws + 23068672);      // 48 MB [3][8192][1024]
    ushort_t* Vt     = (ushort_t*)(ws + 73400320);      // 16 MB [4][1024][2048]
    float*    scores = (float*)   (ws + 90177536);      // 64 MB [4][2048][2048] fp32 / P bf16

    ushort_t* Q = QKV;
    ushort_t* K = QKV + (size_t)8192 * 1024;
    ushort_t* V = QKV + (size_t)2 * 8192 * 1024;

    k_convert_x<<<4096, 256, 0, stream>>>(x, xb);
    k_transpose_w<<<dim3(32, 32, 3), dim3(32, 8), 0, stream>>>(Wq, Wk, Wv, Wt);
    k_proj256<<<dim3(32, 12), 512, 0, stream>>>(xb, Wt, QKV);
    k_transpose_v<<<dim3(32, 64, 4), dim3(32, 8), 0, stream>>>(V, Vt);
    k_gemm<1><<<dim3(136, 1, 4), 256, 0, stream>>>(Q, K, scores);
    k_softmax<<<8192, 256, 0, stream>>>(scores);
    k_gemm<2><<<dim3(16, 8, 4), 256, 0, stream>>>((const ushort_t*)scores, Vt, (float*)d_out);
}

// Round 6
// 181.249 us; speedup vs baseline: 1.1881x; 1.1048x over previous
//
#include <hip/hip_runtime.h>
#include <hip/hip_bf16.h>

typedef __attribute__((ext_vector_type(8))) short short8;
typedef __attribute__((ext_vector_type(4))) float f32x4;
typedef unsigned short ushort_t;

__device__ __forceinline__ ushort_t f2bf(float f) {
    union { __hip_bfloat16 h; ushort_t u; } c;
    c.h = __float2bfloat16(f);
    return c.u;
}

__device__ __forceinline__ void gload16(const ushort_t* g, ushort_t* l) {
    __builtin_amdgcn_global_load_lds(
        (const __attribute__((address_space(1))) void*)g,
        (__attribute__((address_space(3))) void*)l, 16, 0, 0);
}

// ---------------- convert x fp32 -> bf16 ----------------
__global__ __launch_bounds__(256) void k_convert_x(const float* __restrict__ x,
                                                   ushort_t* __restrict__ xb) {
    size_t idx = ((size_t)blockIdx.x * 256 + threadIdx.x) * 8;
    float4 a = *(const float4*)(x + idx);
    float4 b = *(const float4*)(x + idx + 4);
    short8 o;
    o[0] = (short)f2bf(a.x); o[1] = (short)f2bf(a.y);
    o[2] = (short)f2bf(a.z); o[3] = (short)f2bf(a.w);
    o[4] = (short)f2bf(b.x); o[5] = (short)f2bf(b.y);
    o[6] = (short)f2bf(b.z); o[7] = (short)f2bf(b.w);
    *(short8*)(xb + idx) = o;
}

// ---------------- transpose W fp32 [d][e] -> bf16 Wt [e][d], 3 weights -------
__global__ __launch_bounds__(256) void k_transpose_w(const float* __restrict__ W0,
                                                     const float* __restrict__ W1,
                                                     const float* __restrict__ W2,
                                                     ushort_t* __restrict__ Wt) {
    const float* W = (blockIdx.z == 0) ? W0 : (blockIdx.z == 1) ? W1 : W2;
    ushort_t* out = Wt + (size_t)blockIdx.z * 1024 * 1024;
    __shared__ float tile[32][33];
    int tx = threadIdx.x, ty = threadIdx.y;            // 32 x 8
    int d0 = blockIdx.y * 32, e0 = blockIdx.x * 32;
#pragma unroll
    for (int i = 0; i < 32; i += 8)
        tile[ty + i][tx] = W[(size_t)(d0 + ty + i) * 1024 + e0 + tx];
    __syncthreads();
#pragma unroll
    for (int i = 0; i < 32; i += 8)
        out[(size_t)(e0 + ty + i) * 1024 + d0 + tx] = f2bf(tile[tx][ty + i]);
}

// ---------------- transpose V bf16 [b][j][e] -> Vt [b][e][j] ----------------
__global__ __launch_bounds__(256) void k_transpose_v(const ushort_t* __restrict__ V,
                                                     ushort_t* __restrict__ Vt) {
    int b = blockIdx.z;
    const ushort_t* in = V + (size_t)b * 2048 * 1024;
    ushort_t* out = Vt + (size_t)b * 1024 * 2048;
    __shared__ ushort_t tile[32][33];
    int tx = threadIdx.x, ty = threadIdx.y;            // 32 x 8
    int e0 = blockIdx.x * 32, j0 = blockIdx.y * 32;
#pragma unroll
    for (int i = 0; i < 32; i += 8)
        tile[ty + i][tx] = in[(size_t)(j0 + ty + i) * 1024 + e0 + tx];
    __syncthreads();
#pragma unroll
    for (int i = 0; i < 32; i += 8)
        out[(size_t)(e0 + ty + i) * 2048 + j0 + tx] = tile[tx][ty + i];
}

// ---------------- GEMM (m97 128x128): C = A * B^T ----------------
// MODE 0: proj  A=xb[8192][1024]  B=Wt[z][1024][1024]  C=QKV bf16
// MODE 1: qk    triangular grid (136,1,4); writes P' = exp(s/32) bf16, masked 0
// MODE 2: pv    A=P' bf16 lda=2048; B=Vt; rowsum via ones-MFMA; out = acc/rs
template <int MODE>
__global__ __launch_bounds__(256) void k_gemm(const ushort_t* __restrict__ Abase,
                                              const ushort_t* __restrict__ Bbase,
                                              void* __restrict__ Cbase) {
    const int bz = blockIdx.z;
    int bm, bn;
    const ushort_t* A;
    const ushort_t* B;
    int lda, ldb, nk;
    if constexpr (MODE == 0) {
        bm = blockIdx.x; bn = blockIdx.y;
        A = Abase; lda = 1024;
        B = Bbase + (size_t)bz * 1024 * 1024; ldb = 1024;
        nk = 32;
    } else if constexpr (MODE == 1) {
        int x = blockIdx.x;
        bm = (int)((sqrtf(8.f * x + 1.f) - 1.f) * 0.5f);
        while ((bm + 1) * (bm + 2) / 2 <= x) ++bm;
        while (bm * (bm + 1) / 2 > x) --bm;
        bn = x - bm * (bm + 1) / 2;
        A = Abase + (size_t)bz * 2048 * 1024; lda = 1024;
        B = Bbase + (size_t)bz * 2048 * 1024; ldb = 1024;
        nk = 32;
    } else {
        int xr = blockIdx.x;                       // heavy/light interleave
        bm = (xr & 1) ? (15 - (xr >> 1)) : (xr >> 1);
        bn = blockIdx.y;
        A = Abase + (size_t)bz * 2048 * 2048; lda = 2048;
        B = Bbase + (size_t)bz * 1024 * 2048; ldb = 2048;
        nk = (bm + 1) * 4;  // causal K truncation: j <= bm*128+127
    }

    __shared__ ushort_t As[128 * 32];   // linear (gload_lds dest)
    __shared__ ushort_t Bs[128 * 32];

    const int tid = threadIdx.x;
    const int l = tid & 63, wid = tid >> 6;
    const int wr = (wid >> 1) * 64, wc = (wid & 1) * 64;
    const int lr = l & 15, kc = (l >> 4) * 8;

    const int srow = tid >> 2, skb = (tid & 3) * 8;
    const ushort_t* ag = A + (size_t)(bm * 128 + srow) * lda + skb;
    const ushort_t* bg = B + (size_t)(bn * 128 + srow) * ldb + skb;
    const size_t a64 = (size_t)64 * lda, b64 = (size_t)64 * ldb;
    ushort_t* al = As + tid * 8;
    ushort_t* bl = Bs + tid * 8;

    f32x4 zero = {0.f, 0.f, 0.f, 0.f};
    f32x4 acc[4][4];
#pragma unroll
    for (int m = 0; m < 4; ++m)
#pragma unroll
        for (int n = 0; n < 4; ++n) acc[m][n] = zero;

    f32x4 rs[4];            // MODE 2 rowsums
    short8 ones;
#pragma unroll
    for (int e = 0; e < 8; ++e) ones[e] = (short)0x3F80;   // bf16 1.0
#pragma unroll
    for (int m = 0; m < 4; ++m) rs[m] = zero;

    for (int ks = 0; ks < nk; ++ks) {
        __syncthreads();
        gload16(ag, al);
        gload16(ag + a64, al + 2048);
        gload16(bg, bl);
        gload16(bg + b64, bl + 2048);
        ag += 32; bg += 32;
        __syncthreads();

        short8 a[4], b[4];
#pragma unroll
        for (int m = 0; m < 4; ++m)
            a[m] = *(const short8*)&As[(wr + m * 16 + lr) * 32 + kc];
#pragma unroll
        for (int n = 0; n < 4; ++n)
            b[n] = *(const short8*)&Bs[(wc + n * 16 + lr) * 32 + kc];
#pragma unroll
        for (int m = 0; m < 4; ++m)
#pragma unroll
            for (int n = 0; n < 4; ++n)
                acc[m][n] = __builtin_amdgcn_mfma_f32_16x16x32_bf16(a[m], b[n], acc[m][n], 0, 0, 0);
        if constexpr (MODE == 2) {
#pragma unroll
            for (int m = 0; m < 4; ++m)
                rs[m] = __builtin_amdgcn_mfma_f32_16x16x32_bf16(a[m], ones, rs[m], 0, 0, 0);
        }
    }

    const int rbase = (l >> 4) * 4;
    const int cbase = l & 15;

    float inv[4][4];
    if constexpr (MODE == 2) {
#pragma unroll
        for (int m = 0; m < 4; ++m)
#pragma unroll
            for (int r = 0; r < 4; ++r) inv[m][r] = 1.0f / rs[m][r];
    }

#pragma unroll
    for (int m = 0; m < 4; ++m) {
#pragma unroll
        for (int n = 0; n < 4; ++n) {
            int row0 = wr + m * 16 + rbase;
            int col = wc + n * 16 + cbase;
            int gcol = bn * 128 + col;
#pragma unroll
            for (int r = 0; r < 4; ++r) {
                int grow = bm * 128 + row0 + r;
                float v = acc[m][n][r];
                if constexpr (MODE == 0) {
                    ushort_t* C = (ushort_t*)Cbase + (size_t)bz * 8192 * 1024;
                    C[(size_t)grow * 1024 + gcol] = f2bf(v);
                } else if constexpr (MODE == 1) {
                    ushort_t* C = (ushort_t*)Cbase + (size_t)bz * 2048 * 2048;
                    // max-free softmax numerator: exp(s/32), causal mask -> 0
                    ushort_t pv = (gcol <= grow) ? f2bf(__expf(v * 0.03125f))
                                                 : (ushort_t)0;
                    C[(size_t)grow * 2048 + gcol] = pv;
                } else {
                    float* C = (float*)Cbase + (size_t)bz * 2048 * 1024;
                    C[(size_t)grow * 1024 + gcol] = v * inv[m][r];
                }
            }
        }
    }
}

extern "C" void kernel_launch(void* const* d_in, const int* in_sizes, int n_in,
                              void* d_out, int out_size, void* d_ws, size_t ws_size,
                              hipStream_t stream) {
    const float* x  = (const float*)d_in[0];
    const float* Wq = (const float*)d_in[1];
    const float* Wk = (const float*)d_in[2];
    const float* Wv = (const float*)d_in[3];

    char* ws = (char*)d_ws;
    ushort_t* xb     = (ushort_t*)(ws);                 // 16 MB
    ushort_t* Wt     = (ushort_t*)(ws + 16777216);      // 6 MB  [3][1024][1024]
    ushort_t* QKV    = (ushort_t*)(ws + 23068672);      // 48 MB [3][8192][1024]
    ushort_t* Vt     = (ushort_t*)(ws + 73400320);      // 16 MB [4][1024][2048]
    ushort_t* P      = (ushort_t*)(ws + 90177536);      // 32 MB [4][2048][2048] bf16

    ushort_t* Q = QKV;
    ushort_t* K = QKV + (size_t)8192 * 1024;
    ushort_t* V = QKV + (size_t)2 * 8192 * 1024;

    k_convert_x<<<4096, 256, 0, stream>>>(x, xb);
    k_transpose_w<<<dim3(32, 32, 3), dim3(32, 8), 0, stream>>>(Wq, Wk, Wv, Wt);
    k_gemm<0><<<dim3(64, 8, 3), 256, 0, stream>>>(xb, Wt, QKV);
    k_transpose_v<<<dim3(32, 64, 4), dim3(32, 8), 0, stream>>>(V, Vt);
    k_gemm<1><<<dim3(136, 1, 4), 256, 0, stream>>>(Q, K, P);
    k_gemm<2><<<dim3(16, 8, 4), 256, 0, stream>>>(P, Vt, (float*)d_out);
}

// Round 7
// 173.912 us; speedup vs baseline: 1.2383x; 1.0422x over previous
//
#include <hip/hip_runtime.h>
#include <hip/hip_bf16.h>

typedef __attribute__((ext_vector_type(8))) short short8;
typedef __attribute__((ext_vector_type(4))) float f32x4;
typedef unsigned short ushort_t;

__device__ __forceinline__ ushort_t f2bf(float f) {
    union { __hip_bfloat16 h; ushort_t u; } c;
    c.h = __float2bfloat16(f);
    return c.u;
}

__device__ __forceinline__ void gload16(const ushort_t* g, ushort_t* l) {
    __builtin_amdgcn_global_load_lds(
        (const __attribute__((address_space(1))) void*)g,
        (__attribute__((address_space(3))) void*)l, 16, 0, 0);
}

// ---------------- prep: z<3 transpose W_z fp32->bf16; z==3 convert x --------
__global__ __launch_bounds__(256) void k_prep(const float* __restrict__ x,
                                              const float* __restrict__ W0,
                                              const float* __restrict__ W1,
                                              const float* __restrict__ W2,
                                              ushort_t* __restrict__ xb,
                                              ushort_t* __restrict__ Wt) {
    const int bz = blockIdx.z;
    if (bz == 3) {
        // convert x fp32 -> bf16: 1024 blocks x 256 thr x 8 elems x 4 passes
        const int t = threadIdx.y * 32 + threadIdx.x;
        size_t base = ((size_t)(blockIdx.y * 32 + blockIdx.x) * 256 + t) * 8;
#pragma unroll
        for (int p = 0; p < 4; ++p) {
            size_t idx = base + (size_t)p * 2097152;
            float4 a = *(const float4*)(x + idx);
            float4 b = *(const float4*)(x + idx + 4);
            short8 o;
            o[0] = (short)f2bf(a.x); o[1] = (short)f2bf(a.y);
            o[2] = (short)f2bf(a.z); o[3] = (short)f2bf(a.w);
            o[4] = (short)f2bf(b.x); o[5] = (short)f2bf(b.y);
            o[6] = (short)f2bf(b.z); o[7] = (short)f2bf(b.w);
            *(short8*)(xb + idx) = o;
        }
        return;
    }
    const float* W = (bz == 0) ? W0 : (bz == 1) ? W1 : W2;
    ushort_t* out = Wt + (size_t)bz * 1024 * 1024;
    __shared__ float tile[32][33];
    int tx = threadIdx.x, ty = threadIdx.y;            // 32 x 8
    int d0 = blockIdx.y * 32, e0 = blockIdx.x * 32;
#pragma unroll
    for (int i = 0; i < 32; i += 8)
        tile[ty + i][tx] = W[(size_t)(d0 + ty + i) * 1024 + e0 + tx];
    __syncthreads();
#pragma unroll
    for (int i = 0; i < 32; i += 8)
        out[(size_t)(e0 + ty + i) * 1024 + d0 + tx] = f2bf(tile[tx][ty + i]);
}

// ---------------- GEMM (m97 128x128): C = A * B^T ----------------
// MODE 0: proj  A=xb[8192][1024]  B=Wt[z][1024][1024]; z<2 -> QKV bf16;
//               z==2 -> V tile transposed via LDS, written to Vt[b][e][j]
// MODE 1: qk    triangular grid (136,1,4); writes P' = exp(s/32) bf16, masked 0
// MODE 2: pv    A=P' bf16 lda=2048; B=Vt; rowsum via ones-MFMA; out = acc/rs
template <int MODE>
__global__ __launch_bounds__(256) void k_gemm(const ushort_t* __restrict__ Abase,
                                              const ushort_t* __restrict__ Bbase,
                                              void* __restrict__ Cbase,
                                              ushort_t* __restrict__ Vt) {
    const int bz = blockIdx.z;
    int bm, bn;
    const ushort_t* A;
    const ushort_t* B;
    int lda, ldb, nk;
    if constexpr (MODE == 0) {
        bm = blockIdx.x; bn = blockIdx.y;
        A = Abase; lda = 1024;
        B = Bbase + (size_t)bz * 1024 * 1024; ldb = 1024;
        nk = 32;
    } else if constexpr (MODE == 1) {
        int x = blockIdx.x;
        bm = (int)((sqrtf(8.f * x + 1.f) - 1.f) * 0.5f);
        while ((bm + 1) * (bm + 2) / 2 <= x) ++bm;
        while (bm * (bm + 1) / 2 > x) --bm;
        bn = x - bm * (bm + 1) / 2;
        A = Abase + (size_t)bz * 2048 * 1024; lda = 1024;
        B = Bbase + (size_t)bz * 2048 * 1024; ldb = 1024;
        nk = 32;
    } else {
        int xr = blockIdx.x;                       // heavy/light interleave
        bm = (xr & 1) ? (15 - (xr >> 1)) : (xr >> 1);
        bn = blockIdx.y;
        A = Abase + (size_t)bz * 2048 * 2048; lda = 2048;
        B = Bbase + (size_t)bz * 1024 * 2048; ldb = 2048;
        nk = (bm + 1) * 4;  // causal K truncation: j <= bm*128+127
    }

    // MODE 0 reuses smem post-loop as a [128][130] transpose bounce (33.3KB)
    constexpr int SMEM_ELEMS = (MODE == 0) ? (128 * 130) : 8192;
    __shared__ ushort_t smem[SMEM_ELEMS];
    ushort_t* As = smem;          // [128][32] linear (gload_lds dest)
    ushort_t* Bs = smem + 4096;

    const int tid = threadIdx.x;
    const int l = tid & 63, wid = tid >> 6;
    const int wr = (wid >> 1) * 64, wc = (wid & 1) * 64;
    const int lr = l & 15, kc = (l >> 4) * 8;

    const int srow = tid >> 2, skb = (tid & 3) * 8;
    const ushort_t* ag = A + (size_t)(bm * 128 + srow) * lda + skb;
    const ushort_t* bg = B + (size_t)(bn * 128 + srow) * ldb + skb;
    const size_t a64 = (size_t)64 * lda, b64 = (size_t)64 * ldb;
    ushort_t* al = As + tid * 8;
    ushort_t* bl = Bs + tid * 8;

    f32x4 zero = {0.f, 0.f, 0.f, 0.f};
    f32x4 acc[4][4];
#pragma unroll
    for (int m = 0; m < 4; ++m)
#pragma unroll
        for (int n = 0; n < 4; ++n) acc[m][n] = zero;

    f32x4 rs[4];            // MODE 2 rowsums
    short8 ones;
#pragma unroll
    for (int e = 0; e < 8; ++e) ones[e] = (short)0x3F80;   // bf16 1.0
#pragma unroll
    for (int m = 0; m < 4; ++m) rs[m] = zero;

    for (int ks = 0; ks < nk; ++ks) {
        __syncthreads();
        gload16(ag, al);
        gload16(ag + a64, al + 2048);
        gload16(bg, bl);
        gload16(bg + b64, bl + 2048);
        ag += 32; bg += 32;
        __syncthreads();

        short8 a[4], b[4];
#pragma unroll
        for (int m = 0; m < 4; ++m)
            a[m] = *(const short8*)&As[(wr + m * 16 + lr) * 32 + kc];
#pragma unroll
        for (int n = 0; n < 4; ++n)
            b[n] = *(const short8*)&Bs[(wc + n * 16 + lr) * 32 + kc];
#pragma unroll
        for (int m = 0; m < 4; ++m)
#pragma unroll
            for (int n = 0; n < 4; ++n)
                acc[m][n] = __builtin_amdgcn_mfma_f32_16x16x32_bf16(a[m], b[n], acc[m][n], 0, 0, 0);
        if constexpr (MODE == 2) {
#pragma unroll
            for (int m = 0; m < 4; ++m)
                rs[m] = __builtin_amdgcn_mfma_f32_16x16x32_bf16(a[m], ones, rs[m], 0, 0, 0);
        }
    }

    const int rbase = (l >> 4) * 4;
    const int cbase = l & 15;

    if constexpr (MODE == 0) {
        if (bz == 2) {
            // V tile: transpose via LDS, write Vt[b][e][j] (b=batch, j=seq)
            __syncthreads();
#pragma unroll
            for (int m = 0; m < 4; ++m)
#pragma unroll
                for (int n = 0; n < 4; ++n) {
                    int col = wc + n * 16 + cbase;
                    int row0 = wr + m * 16 + rbase;
#pragma unroll
                    for (int r = 0; r < 4; ++r)
                        smem[col * 130 + row0 + r] = f2bf(acc[m][n][r]);
                }
            __syncthreads();
            const int e = tid >> 1, jh = (tid & 1) * 64;
            const int b = bm >> 4, j0 = (bm * 128) & 2047;
            ushort_t* dst = Vt + (size_t)b * 2097152 +
                            (size_t)(bn * 128 + e) * 2048 + j0 + jh;
            const ushort_t* src = smem + e * 130 + jh;
#pragma unroll
            for (int c = 0; c < 8; ++c)
                *(short8*)(dst + c * 8) = *(const short8*)(src + c * 8);
            return;
        }
    }

    float inv[4][4];
    if constexpr (MODE == 2) {
#pragma unroll
        for (int m = 0; m < 4; ++m)
#pragma unroll
            for (int r = 0; r < 4; ++r) inv[m][r] = 1.0f / rs[m][r];
    }

#pragma unroll
    for (int m = 0; m < 4; ++m) {
#pragma unroll
        for (int n = 0; n < 4; ++n) {
            int row0 = wr + m * 16 + rbase;
            int col = wc + n * 16 + cbase;
            int gcol = bn * 128 + col;
#pragma unroll
            for (int r = 0; r < 4; ++r) {
                int grow = bm * 128 + row0 + r;
                float v = acc[m][n][r];
                if constexpr (MODE == 0) {
                    ushort_t* C = (ushort_t*)Cbase + (size_t)bz * 8192 * 1024;
                    C[(size_t)grow * 1024 + gcol] = f2bf(v);
                } else if constexpr (MODE == 1) {
                    ushort_t* C = (ushort_t*)Cbase + (size_t)bz * 2048 * 2048;
                    // max-free softmax numerator: exp(s/32), causal mask -> 0
                    ushort_t pv = (gcol <= grow) ? f2bf(__expf(v * 0.03125f))
                                                 : (ushort_t)0;
                    C[(size_t)grow * 2048 + gcol] = pv;
                } else {
                    float* C = (float*)Cbase + (size_t)bz * 2048 * 1024;
                    C[(size_t)grow * 1024 + gcol] = v * inv[m][r];
                }
            }
        }
    }
}

extern "C" void kernel_launch(void* const* d_in, const int* in_sizes, int n_in,
                              void* d_out, int out_size, void* d_ws, size_t ws_size,
                              hipStream_t stream) {
    const float* x  = (const float*)d_in[0];
    const float* Wq = (const float*)d_in[1];
    const float* Wk = (const float*)d_in[2];
    const float* Wv = (const float*)d_in[3];

    char* ws = (char*)d_ws;
    ushort_t* xb     = (ushort_t*)(ws);                 // 16 MB
    ushort_t* Wt     = (ushort_t*)(ws + 16777216);      // 6 MB  [3][1024][1024]
    ushort_t* QKV    = (ushort_t*)(ws + 23068672);      // 48 MB [3][8192][1024] (z=2 slot unused)
    ushort_t* Vt     = (ushort_t*)(ws + 73400320);      // 16 MB [4][1024][2048]
    ushort_t* P      = (ushort_t*)(ws + 90177536);      // 32 MB [4][2048][2048] bf16

    ushort_t* Q = QKV;
    ushort_t* K = QKV + (size_t)8192 * 1024;

    k_prep<<<dim3(32, 32, 4), dim3(32, 8), 0, stream>>>(x, Wq, Wk, Wv, xb, Wt);
    k_gemm<0><<<dim3(64, 8, 3), 256, 0, stream>>>(xb, Wt, QKV, Vt);
    k_gemm<1><<<dim3(136, 1, 4), 256, 0, stream>>>(Q, K, P, nullptr);
    k_gemm<2><<<dim3(16, 8, 4), 256, 0, stream>>>(P, Vt, (float*)d_out, nullptr);
}